// Round 16
// baseline (189.065 us; speedup 1.0000x reference)
//
#include <hip/hip_runtime.h>
#include <hip/hip_bf16.h>
#include <cstdint>

#define B_  16
#define S_  577
#define D_  768
#define H_  12
#define SP  640           // padded S
#define M_  (B_*S_)       // 9232
#define MP  9344          // padded M (73*128)
#define N_  2304          // combined QKV output dim
#define SCS 664           // sc LDS stride in shorts
#define QSCALE 0.18033688011112042f   // 0.125 * log2(e): scores land in log2 domain

typedef __attribute__((ext_vector_type(8))) short short8;
typedef __attribute__((ext_vector_type(4))) float f32x4;
typedef unsigned int u32;

// HW bf16 conversion (RNE): lowers to v_cvt_pk_bf16_f32 for pairs on gfx950
static __device__ __forceinline__ unsigned short f2bf(float f) {
    __bf16 b = (__bf16)f;
    return __builtin_bit_cast(unsigned short, b);
}
static __device__ __forceinline__ u32 cvtpk(float lo, float hi) {
    return (u32)f2bf(lo) | ((u32)f2bf(hi) << 16);
}
static __device__ __forceinline__ float bf2f(unsigned short u) {
    uint32_t x = ((uint32_t)u) << 16;
    return __builtin_bit_cast(float, x);
}
static __device__ __forceinline__ float exp2_raw(float x) {
    float r;
    asm("v_exp_f32 %0, %1" : "=v"(r) : "v"(x));
    return r;
}

typedef __attribute__((address_space(3))) u32 lds_u32;
typedef __attribute__((address_space(1))) const u32 gbl_u32;
static __device__ __forceinline__ void gll16(const void* g, void* l) {
    __builtin_amdgcn_global_load_lds((gbl_u32*)g, (lds_u32*)l, 16, 0, 0);
}

// Fragment layouts (shorts), d = within-head dim (0..63):
//  Qf: (((b*40+qc)*12+h)*2+dh)*512 + ql*32 + dg*8 + db      q=qc*16+ql, d=dh*32+dg*8+db
//  Kf: (((b*12+h)*10+c)*4+kq)*2+dh)*512 + kl*32 + dg*8 + db key=c*64+kq*16+kl
//  Vf: ((b*12+h)*20+kk)*4+wq)*512 + dl*32 + kg*8 + kb       key=kk*32+kg*8+kb, d=wq*16+dl

// ---------- prep: fp32 -> bf16 of X (zero pad rows) and W; zero Vf pad-key blocks ----------
__global__ __launch_bounds__(256) void prep(
    const float* __restrict__ X,
    const float* __restrict__ Wq, const float* __restrict__ Wk, const float* __restrict__ Wv,
    unsigned short* __restrict__ Xb, unsigned short* __restrict__ Wb,
    unsigned short* __restrict__ Vf)
{
    const int NT1 = MP * 192;
    const int NT2 = N_ * 192;
    const int VPAD = 192 * 1024;               // uint2 stores zeroing kk=18,19 blocks
    const int total = NT1 + NT2 + VPAD;
    const int stride = gridDim.x * 256;
    for (int i = blockIdx.x * 256 + threadIdx.x; i < total; i += stride) {
        if (i < NT1) {
            int row = i / 192, c4 = i - row * 192;
            uint2 out = make_uint2(0u, 0u);
            if (row < M_) {
                float4 v = *(const float4*)(X + (size_t)row * 768 + c4 * 4);
                out.x = cvtpk(v.x, v.y); out.y = cvtpk(v.z, v.w);
            }
            *(uint2*)(Xb + (size_t)row * 768 + c4 * 4) = out;
        } else if (i < NT1 + NT2) {
            int j = i - NT1;
            int row = j / 192, c4 = j - row * 192;
            const float* src = (row < 768) ? (Wq + (size_t)row * 768)
                             : (row < 1536) ? (Wk + (size_t)(row - 768) * 768)
                                            : (Wv + (size_t)(row - 1536) * 768);
            float4 v = *(const float4*)(src + c4 * 4);
            uint2 out;
            out.x = cvtpk(v.x, v.y); out.y = cvtpk(v.z, v.w);
            *(uint2*)(Wb + (size_t)row * 768 + c4 * 4) = out;
        } else {
            int j = i - NT1 - NT2;             // 0..196607
            int bh = j >> 10, rem = j & 1023;  // contiguous 8KB per bh (keys 576..639 region)
            *(uint2*)(Vf + (size_t)bh * 40960 + 36864 + rem * 4) = make_uint2(0u, 0u);
        }
    }
}

// ---------- qkv_gemm: 128x128 tile, 8 waves (64x32 each), BK=64 double-buffered,
// ---------- ONE barrier per K-step (proven R13/R15) + setprio around MFMA ----------
__global__ __launch_bounds__(512) void qkv_gemm(
    const unsigned short* __restrict__ Xb, const unsigned short* __restrict__ Wb,
    const float* __restrict__ bq, const float* __restrict__ bk, const float* __restrict__ bv,
    unsigned short* __restrict__ Qf, unsigned short* __restrict__ Kf,
    unsigned short* __restrict__ Vf)
{
    __shared__ unsigned short Als[2][128 * 64];
    __shared__ unsigned short Bls[2][128 * 64];

    // mts 0..71: XCD-affine (9 per XCD); mt 72's 18 blocks at the tail.
    const int bid = blockIdx.x;                 // grid 1314 = 1296 + 18
    int mt, nt;
    if (bid < 1296) {
        const int xcd = bid & 7, sq = bid >> 3;
        mt = xcd * 9 + sq / 18;
        nt = sq % 18;
    } else {
        mt = 72;
        nt = bid - 1296;
    }

    const bool qk = (nt < 12);
    const int tid = threadIdx.x, lane = tid & 63, wid = tid >> 6;   // wid 0..7
    const int wm = wid >> 2, wn = wid & 3;       // 2x4 wave grid, wave tile 64x32
    const int m0 = mt * 128, n0 = nt * 128;
    const int l15 = lane & 15, g = lane >> 4;
    const int prow = lane >> 3, pc8 = lane & 7;

    f32x4 acc[4][2] = {};    // [A-frag i][B-frag j]

    #define STAGE(buf, kkarg)                                                           \
        {                                                                               \
            _Pragma("unroll")                                                           \
            for (int tt2 = 0; tt2 < 2; ++tt2) {                                         \
                int row  = wid * 16 + tt2 * 8 + prow;                                   \
                int scol = ((pc8 ^ (row & 7)) * 8);                                     \
                gll16(Xb + (size_t)(m0 + row) * 768 + (kkarg) + scol,                   \
                      &Als[buf][(wid * 16 + tt2 * 8) * 64]);                            \
                gll16(Wb + (size_t)(n0 + row) * 768 + (kkarg) + scol,                   \
                      &Bls[buf][(wid * 16 + tt2 * 8) * 64]);                            \
            }                                                                           \
        }

    #define COMPUTE(buf)                                                                \
        {                                                                               \
            const unsigned short* PA = qk ? Bls[buf] : Als[buf];                        \
            const unsigned short* PB = qk ? Als[buf] : Bls[buf];                        \
            _Pragma("unroll")                                                           \
            for (int ks = 0; ks < 2; ++ks) {                                            \
                short8 fa[4], fb[2];                                                    \
                _Pragma("unroll")                                                       \
                for (int i = 0; i < 4; ++i) {                                           \
                    int row = wm * 64 + i * 16 + l15;                                   \
                    fa[i] = *(const short8*)&PA[row * 64 + (((ks * 4 + g) ^ (row & 7)) * 8)]; \
                }                                                                       \
                _Pragma("unroll")                                                       \
                for (int j = 0; j < 2; ++j) {                                           \
                    int row = wn * 32 + j * 16 + l15;                                   \
                    fb[j] = *(const short8*)&PB[row * 64 + (((ks * 4 + g) ^ (row & 7)) * 8)]; \
                }                                                                       \
                __builtin_amdgcn_s_setprio(1);                                          \
                _Pragma("unroll")                                                       \
                for (int i = 0; i < 4; ++i)                                             \
                    _Pragma("unroll")                                                   \
                    for (int j = 0; j < 2; ++j)                                         \
                        acc[i][j] = __builtin_amdgcn_mfma_f32_16x16x32_bf16(            \
                            fa[i], fb[j], acc[i][j], 0, 0, 0);                          \
                __builtin_amdgcn_s_setprio(0);                                          \
            }                                                                           \
        }

    STAGE(0, 0);
    __syncthreads();
    int cur = 0;
    #pragma unroll 1
    for (int t = 0; t < 12; ++t) {
        if (t < 11) STAGE(cur ^ 1, (t + 1) * 64);
        COMPUTE(cur);
        __syncthreads();      // drains vmcnt(0) (next-buffer DMA) + lgkmcnt (this-buffer reads)
        cur ^= 1;
    }
    #undef STAGE
    #undef COMPUTE

    if (qk) {
        // A=W: D rows = n (d-dim), cols = m. Offsets split: off = Pj(b,s) + Pi(n).
        const float* bb = (nt < 6) ? bq : bk;
        unsigned short* Dst = (nt < 6) ? Qf : Kf;
        const float scale = (nt < 6) ? QSCALE : 1.0f;
        const int n0p = n0 - ((nt < 6) ? 0 : 768);

        float4 b4[4]; int Pi[4];
        #pragma unroll
        for (int i = 0; i < 4; ++i) {
            int nrow0 = n0p + wm * 64 + i * 16 + g * 4;     // 4-aligned
            b4[i] = *(const float4*)(bb + nrow0);
            int hh = nrow0 >> 6, d0 = nrow0 & 63;
            int base = (d0 >> 5) * 512 + ((d0 >> 3) & 3) * 8 + (d0 & 7);
            Pi[i] = ((nt < 6) ? hh * 1024 : hh * 40960) + base;
        }
        #pragma unroll
        for (int j = 0; j < 2; ++j) {
            int m = m0 + wn * 32 + j * 16 + l15;
            if (m >= M_) continue;
            int b = m / 577, s = m - b * 577;
            int Pj = (nt < 6)
                   ? b * 491520 + (s >> 4) * 12288 + (s & 15) * 32
                   : b * 491520 + (s >> 6) * 4096 + ((s >> 4) & 3) * 1024 + (s & 15) * 32;
            #pragma unroll
            for (int i = 0; i < 4; ++i) {
                uint2 p;
                p.x = cvtpk((acc[i][j][0] + b4[i].x) * scale, (acc[i][j][1] + b4[i].y) * scale);
                p.y = cvtpk((acc[i][j][2] + b4[i].z) * scale, (acc[i][j][3] + b4[i].w) * scale);
                *(uint2*)(Dst + Pj + Pi[i]) = p;
            }
        }
    } else {
        // A=X: D rows = m (s), cols = n (d). Offsets split: off = Pir(b,s) + Pn(n).
        int Pir[4][4]; bool mv[4][4];
        #pragma unroll
        for (int i = 0; i < 4; ++i) {
            int mi = m0 + wm * 64 + i * 16 + g * 4;
            int b = mi / 577, s = mi - b * 577;
            #pragma unroll
            for (int r = 0; r < 4; ++r) {
                int bb2 = b, ss = s + r;
                if (ss >= 577) { bb2++; ss -= 577; }
                mv[i][r] = (mi + r < M_);
                Pir[i][r] = bb2 * 491520 + (ss >> 5) * 2048 + ((ss >> 3) & 3) * 8 + (ss & 7);
            }
        }
        #pragma unroll
        for (int j = 0; j < 2; ++j) {
            int nn = n0 + wn * 32 + j * 16 + l15 - 1536;
            float bias = bv[nn];
            int hh = nn >> 6, dwh = nn & 63;
            int Pn = hh * 40960 + (dwh >> 4) * 512 + (dwh & 15) * 32;
            #pragma unroll
            for (int i = 0; i < 4; ++i)
                #pragma unroll
                for (int r = 0; r < 4; ++r)
                    if (mv[i][r])
                        Vf[Pn + Pir[i][r]] = f2bf(acc[i][j][r] + bias);
        }
    }
}

// ---------- attn: 5-deep register-rotation QK/PV (low VGPR, deep ILP), 4 blocks/CU ----------
__global__ __launch_bounds__(256, 4) void attn(
    const unsigned short* __restrict__ Qf, const unsigned short* __restrict__ Kf,
    const unsigned short* __restrict__ Vf,
    float* __restrict__ ctx, float* __restrict__ probs)
{
    __shared__ unsigned short sc[16 * SCS];
    __shared__ float rowinv[16];

    const int wg  = blockIdx.x;                 // 7104 = 8 * 888, bijective XCD swizzle
    const int idx = (wg & 7) * 888 + (wg >> 3);
    const int bh  = idx / 37;
    const int qt  = idx - bh * 37;
    const int h   = bh % 12, b = bh / 12;

    const int tid = threadIdx.x, lane = tid & 63, wid = tid >> 6;
    const int l15 = lane & 15, g = lane >> 4;
    const int q0 = qt * 16;
    const int lofs = l15 * 32 + g * 8;
    const int r = tid >> 4, c0 = tid & 15;

    const unsigned short* qb = Qf + ((size_t)(b * 40 + qt) * 12 + h) * 1024 + lofs;
    short8 aq0 = *(const short8*)qb;
    short8 aq1 = *(const short8*)(qb + 512);

    // QK^T: 5-deep rotation — preload 5 chunk-pairs, refill slot right after its read.
    const unsigned short* kb0 = Kf + (size_t)bh * 40960 + wid * 1024 + lofs;
    short8 ka[5], kb_[5];
    #pragma unroll
    for (int c = 0; c < 5; ++c) {
        ka[c]  = *(const short8*)(kb0 + c * 4096);
        kb_[c] = *(const short8*)(kb0 + c * 4096 + 512);
    }
    #pragma unroll
    for (int c = 0; c < 10; ++c) {
        short8 a0 = ka[c % 5], a1 = kb_[c % 5];
        if (c < 5) {            // refill this slot with chunk c+5 (loads overlap MFMAs)
            ka[c]  = *(const short8*)(kb0 + (c + 5) * 4096);
            kb_[c] = *(const short8*)(kb0 + (c + 5) * 4096 + 512);
        }
        f32x4 s4 = {};
        __builtin_amdgcn_s_setprio(1);
        s4 = __builtin_amdgcn_mfma_f32_16x16x32_bf16(aq0, a0, s4, 0, 0, 0);
        s4 = __builtin_amdgcn_mfma_f32_16x16x32_bf16(aq1, a1, s4, 0, 0, 0);
        __builtin_amdgcn_s_setprio(0);
        int key = c * 64 + wid * 16 + l15;
        #pragma unroll
        for (int rr = 0; rr < 4; ++rr)
            sc[(g * 4 + rr) * SCS + key] = (key < S_) ? f2bf(s4[rr]) : (unsigned short)0xFF80u; // -inf
    }
    __syncthreads();

    // softmax (log2 domain): 16 threads per row; tree reductions, raw v_exp
    unsigned short* rowp = &sc[r * SCS];
    float inv;
    {
        float m = -1e30f;
        #pragma unroll
        for (int i = 0; i < 5; ++i) {
            short8 v = *(const short8*)&rowp[(c0 + 16 * i) * 8];
            float t0 = fmaxf(bf2f((unsigned short)v[0]), bf2f((unsigned short)v[1]));
            float t1 = fmaxf(bf2f((unsigned short)v[2]), bf2f((unsigned short)v[3]));
            float t2 = fmaxf(bf2f((unsigned short)v[4]), bf2f((unsigned short)v[5]));
            float t3 = fmaxf(bf2f((unsigned short)v[6]), bf2f((unsigned short)v[7]));
            m = fmaxf(m, fmaxf(fmaxf(t0, t1), fmaxf(t2, t3)));
        }
        #pragma unroll
        for (int o = 8; o; o >>= 1) m = fmaxf(m, __shfl_xor(m, o));

        float ssum = 0.f;
        #pragma unroll
        for (int i = 0; i < 5; ++i) {
            short8 v = *(const short8*)&rowp[(c0 + 16 * i) * 8];
            float e0 = exp2_raw(bf2f((unsigned short)v[0]) - m);
            float e1 = exp2_raw(bf2f((unsigned short)v[1]) - m);
            float e2 = exp2_raw(bf2f((unsigned short)v[2]) - m);
            float e3 = exp2_raw(bf2f((unsigned short)v[3]) - m);
            float e4 = exp2_raw(bf2f((unsigned short)v[4]) - m);
            float e5 = exp2_raw(bf2f((unsigned short)v[5]) - m);
            float e6 = exp2_raw(bf2f((unsigned short)v[6]) - m);
            float e7 = exp2_raw(bf2f((unsigned short)v[7]) - m);
            uint4 w;
            w.x = cvtpk(e0, e1); w.y = cvtpk(e2, e3);
            w.z = cvtpk(e4, e5); w.w = cvtpk(e6, e7);
            *(uint4*)&rowp[(c0 + 16 * i) * 8] = w;
            ssum += ((e0 + e1) + (e2 + e3)) + ((e4 + e5) + (e6 + e7));
        }
        #pragma unroll
        for (int o = 8; o; o >>= 1) ssum += __shfl_xor(ssum, o);
        inv = 1.0f / ssum;
        if (c0 == 0) rowinv[r] = inv;
    }
    __syncthreads();

    // PV rotation batch 0: issue 5 fragment-pairs now; probs-write hides their latency (T14)
    const unsigned short* vb0 = Vf + (size_t)bh * 40960 + wid * 512 + lofs;
    short8 va[5], vb_[5];
    #pragma unroll
    for (int k = 0; k < 5; ++k) {
        va[k]  = *(const short8*)(vb0 + (size_t)(2 * k) * 2048);
        vb_[k] = *(const short8*)(vb0 + (size_t)(2 * k + 1) * 2048);
    }

    // probs write: nt stores drain under PV's MFMA / later blocks
    {
        int q = q0 + r;
        if (q < S_) {
            float* prow = probs + ((size_t)bh * S_ + q) * S_;
            #pragma unroll
            for (int i = 0; i < 5; ++i) {
                int ch = c0 + 16 * i;
                short8 v = *(const short8*)&rowp[ch * 8];
                if (ch < 72) {
                    f32x4 o0, o1;
                    o0[0] = bf2f((unsigned short)v[0]) * inv; o0[1] = bf2f((unsigned short)v[1]) * inv;
                    o0[2] = bf2f((unsigned short)v[2]) * inv; o0[3] = bf2f((unsigned short)v[3]) * inv;
                    o1[0] = bf2f((unsigned short)v[4]) * inv; o1[1] = bf2f((unsigned short)v[5]) * inv;
                    o1[2] = bf2f((unsigned short)v[6]) * inv; o1[3] = bf2f((unsigned short)v[7]) * inv;
                    __builtin_nontemporal_store(o0, (f32x4*)&prow[ch * 8]);
                    __builtin_nontemporal_store(o1, (f32x4*)&prow[ch * 8 + 4]);
                } else if (ch == 72) {
                    __builtin_nontemporal_store(bf2f((unsigned short)v[0]) * inv, &prow[576]);
                }
            }
        }
    }

    // PV: 5-deep rotation; wave wid owns d-slice [wid*16, wid*16+16)
    f32x4 oc0 = {}, oc1 = {};
    const unsigned short* pb = &sc[l15 * SCS + g * 8];
    #pragma unroll
    for (int kk = 0; kk < 10; ++kk) {
        short8 a0 = va[kk % 5], a1 = vb_[kk % 5];
        if (kk < 5) {           // refill with pair kk+5 (loads overlap MFMAs)
            va[kk]  = *(const short8*)(vb0 + (size_t)(2 * (kk + 5)) * 2048);
            vb_[kk] = *(const short8*)(vb0 + (size_t)(2 * (kk + 5) + 1) * 2048);
        }
        short8 ap0 = *(const short8*)(pb + (2 * kk) * 32);
        short8 ap1 = *(const short8*)(pb + (2 * kk + 1) * 32);
        __builtin_amdgcn_s_setprio(1);
        oc0 = __builtin_amdgcn_mfma_f32_16x16x32_bf16(ap0, a0, oc0, 0, 0, 0);
        oc1 = __builtin_amdgcn_mfma_f32_16x16x32_bf16(ap1, a1, oc1, 0, 0, 0);
        __builtin_amdgcn_s_setprio(0);
    }
    f32x4 oc = oc0 + oc1;
    #pragma unroll
    for (int rr = 0; rr < 4; ++rr) {
        int qr = g * 4 + rr;
        int qq = q0 + qr;
        if (qq < S_)
            __builtin_nontemporal_store(oc[rr] * rowinv[qr],
                &ctx[((size_t)b * S_ + qq) * D_ + h * 64 + wid * 16 + l15]);
    }
}

extern "C" void kernel_launch(void* const* d_in, const int* in_sizes, int n_in,
                              void* d_out, int out_size, void* d_ws, size_t ws_size,
                              hipStream_t stream) {
    const float* X  = (const float*)d_in[0];
    const float* Wq = (const float*)d_in[1];
    const float* bq = (const float*)d_in[2];
    const float* Wk = (const float*)d_in[3];
    const float* bk = (const float*)d_in[4];
    const float* Wv = (const float*)d_in[5];
    const float* bv = (const float*)d_in[6];

    float* ctx   = (float*)d_out;
    float* probs = ctx + (size_t)B_ * S_ * D_;

    unsigned short* Xb = (unsigned short*)probs;            // staged in probs region
    unsigned short* Wb = Xb + (size_t)MP * 768;

    unsigned short* Qf = (unsigned short*)d_ws;
    unsigned short* Kf = Qf + (size_t)7864320;
    unsigned short* Vf = Kf + (size_t)7864320;

    prep<<<dim3(1024), 256, 0, stream>>>(X, Wq, Wk, Wv, Xb, Wb, Vf);
    qkv_gemm<<<dim3(1314), 512, 0, stream>>>(Xb, Wb, bq, bk, bv, Qf, Kf, Vf);
    attn<<<dim3(7104), 256, 0, stream>>>(Qf, Kf, Vf, ctx, probs);
}

// Round 17
// 180.720 us; speedup vs baseline: 1.0462x; 1.0462x over previous
//
#include <hip/hip_runtime.h>
#include <hip/hip_bf16.h>
#include <cstdint>

#define B_  16
#define S_  577
#define D_  768
#define H_  12
#define SP  640           // padded S
#define M_  (B_*S_)       // 9232
#define MP  9344          // padded M (73*128)
#define N_  2304          // combined QKV output dim
#define SCS 664           // sc LDS stride in shorts
#define QSCALE 0.18033688011112042f   // 0.125 * log2(e): scores land in log2 domain

typedef __attribute__((ext_vector_type(8))) short short8;
typedef __attribute__((ext_vector_type(4))) float f32x4;
typedef unsigned int u32;

// HW bf16 conversion (RNE): lowers to v_cvt_pk_bf16_f32 for pairs on gfx950
static __device__ __forceinline__ unsigned short f2bf(float f) {
    __bf16 b = (__bf16)f;
    return __builtin_bit_cast(unsigned short, b);
}
static __device__ __forceinline__ u32 cvtpk(float lo, float hi) {
    return (u32)f2bf(lo) | ((u32)f2bf(hi) << 16);
}
static __device__ __forceinline__ float bf2f(unsigned short u) {
    uint32_t x = ((uint32_t)u) << 16;
    return __builtin_bit_cast(float, x);
}
static __device__ __forceinline__ float exp2_raw(float x) {
    float r;
    asm("v_exp_f32 %0, %1" : "=v"(r) : "v"(x));
    return r;
}

typedef __attribute__((address_space(3))) u32 lds_u32;
typedef __attribute__((address_space(1))) const u32 gbl_u32;
static __device__ __forceinline__ void gll16(const void* g, void* l) {
    __builtin_amdgcn_global_load_lds((gbl_u32*)g, (lds_u32*)l, 16, 0, 0);
}

// Fragment layouts (shorts), d = within-head dim (0..63):
//  Qf: (((b*40+qc)*12+h)*2+dh)*512 + ql*32 + dg*8 + db      q=qc*16+ql, d=dh*32+dg*8+db
//  Kf: (((b*12+h)*10+c)*4+kq)*2+dh)*512 + kl*32 + dg*8 + db key=c*64+kq*16+kl
//  Vf: ((b*12+h)*20+kk)*4+wq)*512 + dl*32 + kg*8 + kb       key=kk*32+kg*8+kb, d=wq*16+dl

// ---------- prep: fp32 -> bf16 of X (zero pad rows) and W; zero Vf pad-key blocks ----------
__global__ __launch_bounds__(256) void prep(
    const float* __restrict__ X,
    const float* __restrict__ Wq, const float* __restrict__ Wk, const float* __restrict__ Wv,
    unsigned short* __restrict__ Xb, unsigned short* __restrict__ Wb,
    unsigned short* __restrict__ Vf)
{
    const int NT1 = MP * 192;
    const int NT2 = N_ * 192;
    const int VPAD = 192 * 1024;               // uint2 stores zeroing kk=18,19 blocks
    const int total = NT1 + NT2 + VPAD;
    const int stride = gridDim.x * 256;
    for (int i = blockIdx.x * 256 + threadIdx.x; i < total; i += stride) {
        if (i < NT1) {
            int row = i / 192, c4 = i - row * 192;
            uint2 out = make_uint2(0u, 0u);
            if (row < M_) {
                float4 v = *(const float4*)(X + (size_t)row * 768 + c4 * 4);
                out.x = cvtpk(v.x, v.y); out.y = cvtpk(v.z, v.w);
            }
            *(uint2*)(Xb + (size_t)row * 768 + c4 * 4) = out;
        } else if (i < NT1 + NT2) {
            int j = i - NT1;
            int row = j / 192, c4 = j - row * 192;
            const float* src = (row < 768) ? (Wq + (size_t)row * 768)
                             : (row < 1536) ? (Wk + (size_t)(row - 768) * 768)
                                            : (Wv + (size_t)(row - 1536) * 768);
            float4 v = *(const float4*)(src + c4 * 4);
            uint2 out;
            out.x = cvtpk(v.x, v.y); out.y = cvtpk(v.z, v.w);
            *(uint2*)(Wb + (size_t)row * 768 + c4 * 4) = out;
        } else {
            int j = i - NT1 - NT2;             // 0..196607
            int bh = j >> 10, rem = j & 1023;  // contiguous 8KB per bh (keys 576..639 region)
            *(uint2*)(Vf + (size_t)bh * 40960 + 36864 + rem * 4) = make_uint2(0u, 0u);
        }
    }
}

// ---------- qkv_gemm: 128x128 tile, 8 waves (64x32 each), BK=64 double-buffered,
// ---------- ONE barrier per K-step (proven R13/R15) + setprio around MFMA ----------
__global__ __launch_bounds__(512) void qkv_gemm(
    const unsigned short* __restrict__ Xb, const unsigned short* __restrict__ Wb,
    const float* __restrict__ bq, const float* __restrict__ bk, const float* __restrict__ bv,
    unsigned short* __restrict__ Qf, unsigned short* __restrict__ Kf,
    unsigned short* __restrict__ Vf)
{
    __shared__ unsigned short Als[2][128 * 64];
    __shared__ unsigned short Bls[2][128 * 64];

    // mts 0..71: XCD-affine (9 per XCD); mt 72's 18 blocks at the tail.
    const int bid = blockIdx.x;                 // grid 1314 = 1296 + 18
    int mt, nt;
    if (bid < 1296) {
        const int xcd = bid & 7, sq = bid >> 3;
        mt = xcd * 9 + sq / 18;
        nt = sq % 18;
    } else {
        mt = 72;
        nt = bid - 1296;
    }

    const bool qk = (nt < 12);
    const int tid = threadIdx.x, lane = tid & 63, wid = tid >> 6;   // wid 0..7
    const int wm = wid >> 2, wn = wid & 3;       // 2x4 wave grid, wave tile 64x32
    const int m0 = mt * 128, n0 = nt * 128;
    const int l15 = lane & 15, g = lane >> 4;
    const int prow = lane >> 3, pc8 = lane & 7;

    f32x4 acc[4][2] = {};    // [A-frag i][B-frag j]

    #define STAGE(buf, kkarg)                                                           \
        {                                                                               \
            _Pragma("unroll")                                                           \
            for (int tt2 = 0; tt2 < 2; ++tt2) {                                         \
                int row  = wid * 16 + tt2 * 8 + prow;                                   \
                int scol = ((pc8 ^ (row & 7)) * 8);                                     \
                gll16(Xb + (size_t)(m0 + row) * 768 + (kkarg) + scol,                   \
                      &Als[buf][(wid * 16 + tt2 * 8) * 64]);                            \
                gll16(Wb + (size_t)(n0 + row) * 768 + (kkarg) + scol,                   \
                      &Bls[buf][(wid * 16 + tt2 * 8) * 64]);                            \
            }                                                                           \
        }

    #define COMPUTE(buf)                                                                \
        {                                                                               \
            const unsigned short* PA = qk ? Bls[buf] : Als[buf];                        \
            const unsigned short* PB = qk ? Als[buf] : Bls[buf];                        \
            _Pragma("unroll")                                                           \
            for (int ks = 0; ks < 2; ++ks) {                                            \
                short8 fa[4], fb[2];                                                    \
                _Pragma("unroll")                                                       \
                for (int i = 0; i < 4; ++i) {                                           \
                    int row = wm * 64 + i * 16 + l15;                                   \
                    fa[i] = *(const short8*)&PA[row * 64 + (((ks * 4 + g) ^ (row & 7)) * 8)]; \
                }                                                                       \
                _Pragma("unroll")                                                       \
                for (int j = 0; j < 2; ++j) {                                           \
                    int row = wn * 32 + j * 16 + l15;                                   \
                    fb[j] = *(const short8*)&PB[row * 64 + (((ks * 4 + g) ^ (row & 7)) * 8)]; \
                }                                                                       \
                __builtin_amdgcn_s_setprio(1);                                          \
                _Pragma("unroll")                                                       \
                for (int i = 0; i < 4; ++i)                                             \
                    _Pragma("unroll")                                                   \
                    for (int j = 0; j < 2; ++j)                                         \
                        acc[i][j] = __builtin_amdgcn_mfma_f32_16x16x32_bf16(            \
                            fa[i], fb[j], acc[i][j], 0, 0, 0);                          \
                __builtin_amdgcn_s_setprio(0);                                          \
            }                                                                           \
        }

    STAGE(0, 0);
    __syncthreads();
    int cur = 0;
    #pragma unroll 1
    for (int t = 0; t < 12; ++t) {
        if (t < 11) STAGE(cur ^ 1, (t + 1) * 64);
        COMPUTE(cur);
        __syncthreads();      // drains vmcnt(0) (next-buffer DMA) + lgkmcnt (this-buffer reads)
        cur ^= 1;
    }
    #undef STAGE
    #undef COMPUTE

    if (qk) {
        // A=W: D rows = n (d-dim), cols = m. Offsets split: off = Pj(b,s) + Pi(n).
        const float* bb = (nt < 6) ? bq : bk;
        unsigned short* Dst = (nt < 6) ? Qf : Kf;
        const float scale = (nt < 6) ? QSCALE : 1.0f;
        const int n0p = n0 - ((nt < 6) ? 0 : 768);

        float4 b4[4]; int Pi[4];
        #pragma unroll
        for (int i = 0; i < 4; ++i) {
            int nrow0 = n0p + wm * 64 + i * 16 + g * 4;     // 4-aligned
            b4[i] = *(const float4*)(bb + nrow0);
            int hh = nrow0 >> 6, d0 = nrow0 & 63;
            int base = (d0 >> 5) * 512 + ((d0 >> 3) & 3) * 8 + (d0 & 7);
            Pi[i] = ((nt < 6) ? hh * 1024 : hh * 40960) + base;
        }
        #pragma unroll
        for (int j = 0; j < 2; ++j) {
            int m = m0 + wn * 32 + j * 16 + l15;
            if (m >= M_) continue;
            int b = m / 577, s = m - b * 577;
            int Pj = (nt < 6)
                   ? b * 491520 + (s >> 4) * 12288 + (s & 15) * 32
                   : b * 491520 + (s >> 6) * 4096 + ((s >> 4) & 3) * 1024 + (s & 15) * 32;
            #pragma unroll
            for (int i = 0; i < 4; ++i) {
                uint2 p;
                p.x = cvtpk((acc[i][j][0] + b4[i].x) * scale, (acc[i][j][1] + b4[i].y) * scale);
                p.y = cvtpk((acc[i][j][2] + b4[i].z) * scale, (acc[i][j][3] + b4[i].w) * scale);
                *(uint2*)(Dst + Pj + Pi[i]) = p;
            }
        }
    } else {
        // A=X: D rows = m (s), cols = n (d). Offsets split: off = Pir(b,s) + Pn(n).
        int Pir[4][4]; bool mv[4][4];
        #pragma unroll
        for (int i = 0; i < 4; ++i) {
            int mi = m0 + wm * 64 + i * 16 + g * 4;
            int b = mi / 577, s = mi - b * 577;
            #pragma unroll
            for (int r = 0; r < 4; ++r) {
                int bb2 = b, ss = s + r;
                if (ss >= 577) { bb2++; ss -= 577; }
                mv[i][r] = (mi + r < M_);
                Pir[i][r] = bb2 * 491520 + (ss >> 5) * 2048 + ((ss >> 3) & 3) * 8 + (ss & 7);
            }
        }
        #pragma unroll
        for (int j = 0; j < 2; ++j) {
            int nn = n0 + wn * 32 + j * 16 + l15 - 1536;
            float bias = bv[nn];
            int hh = nn >> 6, dwh = nn & 63;
            int Pn = hh * 40960 + (dwh >> 4) * 512 + (dwh & 15) * 32;
            #pragma unroll
            for (int i = 0; i < 4; ++i)
                #pragma unroll
                for (int r = 0; r < 4; ++r)
                    if (mv[i][r])
                        Vf[Pn + Pir[i][r]] = f2bf(acc[i][j][r] + bias);
        }
    }
}

// ---------- attn (R13-proven) + setprio around MFMA clusters ----------
__global__ __launch_bounds__(256) void attn(
    const unsigned short* __restrict__ Qf, const unsigned short* __restrict__ Kf,
    const unsigned short* __restrict__ Vf,
    float* __restrict__ ctx, float* __restrict__ probs)
{
    __shared__ unsigned short sc[16 * SCS];
    __shared__ float rowinv[16];

    const int wg  = blockIdx.x;                 // 7104 = 8 * 888, bijective XCD swizzle
    const int idx = (wg & 7) * 888 + (wg >> 3);
    const int bh  = idx / 37;
    const int qt  = idx - bh * 37;
    const int h   = bh % 12, b = bh / 12;

    const int tid = threadIdx.x, lane = tid & 63, wid = tid >> 6;
    const int l15 = lane & 15, g = lane >> 4;
    const int q0 = qt * 16;
    const int lofs = l15 * 32 + g * 8;
    const int r = tid >> 4, c0 = tid & 15;

    const unsigned short* qb = Qf + ((size_t)(b * 40 + qt) * 12 + h) * 1024 + lofs;
    short8 aq0 = *(const short8*)qb;
    short8 aq1 = *(const short8*)(qb + 512);

    // QK^T: batch ALL 20 K fragments into registers (20 loads in flight)
    const unsigned short* kb0 = Kf + (size_t)bh * 40960 + wid * 1024 + lofs;
    short8 kr0[10], kr1[10];
    #pragma unroll
    for (int c = 0; c < 10; ++c) {
        const unsigned short* kb = kb0 + c * 4096;
        kr0[c] = *(const short8*)kb;
        kr1[c] = *(const short8*)(kb + 512);
    }
    #pragma unroll
    for (int c = 0; c < 10; ++c) {
        f32x4 s4 = {};
        __builtin_amdgcn_s_setprio(1);
        s4 = __builtin_amdgcn_mfma_f32_16x16x32_bf16(aq0, kr0[c], s4, 0, 0, 0);
        s4 = __builtin_amdgcn_mfma_f32_16x16x32_bf16(aq1, kr1[c], s4, 0, 0, 0);
        __builtin_amdgcn_s_setprio(0);
        int key = c * 64 + wid * 16 + l15;
        #pragma unroll
        for (int rr = 0; rr < 4; ++rr)
            sc[(g * 4 + rr) * SCS + key] = (key < S_) ? f2bf(s4[rr]) : (unsigned short)0xFF80u; // -inf
    }
    __syncthreads();

    // softmax (log2 domain): 16 threads per row; tree reductions, raw v_exp
    unsigned short* rowp = &sc[r * SCS];
    float inv;
    {
        float m = -1e30f;
        #pragma unroll
        for (int i = 0; i < 5; ++i) {
            short8 v = *(const short8*)&rowp[(c0 + 16 * i) * 8];
            float t0 = fmaxf(bf2f((unsigned short)v[0]), bf2f((unsigned short)v[1]));
            float t1 = fmaxf(bf2f((unsigned short)v[2]), bf2f((unsigned short)v[3]));
            float t2 = fmaxf(bf2f((unsigned short)v[4]), bf2f((unsigned short)v[5]));
            float t3 = fmaxf(bf2f((unsigned short)v[6]), bf2f((unsigned short)v[7]));
            m = fmaxf(m, fmaxf(fmaxf(t0, t1), fmaxf(t2, t3)));
        }
        #pragma unroll
        for (int o = 8; o; o >>= 1) m = fmaxf(m, __shfl_xor(m, o));

        float ssum = 0.f;
        #pragma unroll
        for (int i = 0; i < 5; ++i) {
            short8 v = *(const short8*)&rowp[(c0 + 16 * i) * 8];
            float e0 = exp2_raw(bf2f((unsigned short)v[0]) - m);
            float e1 = exp2_raw(bf2f((unsigned short)v[1]) - m);
            float e2 = exp2_raw(bf2f((unsigned short)v[2]) - m);
            float e3 = exp2_raw(bf2f((unsigned short)v[3]) - m);
            float e4 = exp2_raw(bf2f((unsigned short)v[4]) - m);
            float e5 = exp2_raw(bf2f((unsigned short)v[5]) - m);
            float e6 = exp2_raw(bf2f((unsigned short)v[6]) - m);
            float e7 = exp2_raw(bf2f((unsigned short)v[7]) - m);
            uint4 w;
            w.x = cvtpk(e0, e1); w.y = cvtpk(e2, e3);
            w.z = cvtpk(e4, e5); w.w = cvtpk(e6, e7);
            *(uint4*)&rowp[(c0 + 16 * i) * 8] = w;
            ssum += ((e0 + e1) + (e2 + e3)) + ((e4 + e5) + (e6 + e7));
        }
        #pragma unroll
        for (int o = 8; o; o >>= 1) ssum += __shfl_xor(ssum, o);
        inv = 1.0f / ssum;
        if (c0 == 0) rowinv[r] = inv;
    }
    __syncthreads();

    // T14: issue ALL 20 V-fragment loads now; the probs-write phase below
    // (VALU + nt stores, no dependence on V) hides their L2/HBM latency.
    const unsigned short* vb0 = Vf + (size_t)bh * 40960 + wid * 512 + lofs;
    short8 vr0[10], vr1[10];
    #pragma unroll
    for (int kk = 0; kk < 10; ++kk) {
        vr0[kk] = *(const short8*)(vb0 + (size_t)(2 * kk) * 2048);
        vr1[kk] = *(const short8*)(vb0 + (size_t)(2 * kk + 1) * 2048);
    }

    // probs write: nt stores drain under PV's MFMA / later blocks
    {
        int q = q0 + r;
        if (q < S_) {
            float* prow = probs + ((size_t)bh * S_ + q) * S_;
            #pragma unroll
            for (int i = 0; i < 5; ++i) {
                int ch = c0 + 16 * i;
                short8 v = *(const short8*)&rowp[ch * 8];
                if (ch < 72) {
                    f32x4 o0, o1;
                    o0[0] = bf2f((unsigned short)v[0]) * inv; o0[1] = bf2f((unsigned short)v[1]) * inv;
                    o0[2] = bf2f((unsigned short)v[2]) * inv; o0[3] = bf2f((unsigned short)v[3]) * inv;
                    o1[0] = bf2f((unsigned short)v[4]) * inv; o1[1] = bf2f((unsigned short)v[5]) * inv;
                    o1[2] = bf2f((unsigned short)v[6]) * inv; o1[3] = bf2f((unsigned short)v[7]) * inv;
                    __builtin_nontemporal_store(o0, (f32x4*)&prow[ch * 8]);
                    __builtin_nontemporal_store(o1, (f32x4*)&prow[ch * 8 + 4]);
                } else if (ch == 72) {
                    __builtin_nontemporal_store(bf2f((unsigned short)v[0]) * inv, &prow[576]);
                }
            }
        }
    }

    // PV: wave wid owns d-slice [wid*16, wid*16+16); V already in registers
    f32x4 oc0 = {}, oc1 = {};
    const unsigned short* pb = &sc[l15 * SCS + g * 8];
    #pragma unroll
    for (int kk = 0; kk < 10; ++kk) {
        short8 ap0 = *(const short8*)(pb + (2 * kk) * 32);
        short8 ap1 = *(const short8*)(pb + (2 * kk + 1) * 32);
        __builtin_amdgcn_s_setprio(1);
        oc0 = __builtin_amdgcn_mfma_f32_16x16x32_bf16(ap0, vr0[kk], oc0, 0, 0, 0);
        oc1 = __builtin_amdgcn_mfma_f32_16x16x32_bf16(ap1, vr1[kk], oc1, 0, 0, 0);
        __builtin_amdgcn_s_setprio(0);
    }
    f32x4 oc = oc0 + oc1;
    #pragma unroll
    for (int rr = 0; rr < 4; ++rr) {
        int qr = g * 4 + rr;
        int qq = q0 + qr;
        if (qq < S_)
            __builtin_nontemporal_store(oc[rr] * rowinv[qr],
                &ctx[((size_t)b * S_ + qq) * D_ + h * 64 + wid * 16 + l15]);
    }
}

extern "C" void kernel_launch(void* const* d_in, const int* in_sizes, int n_in,
                              void* d_out, int out_size, void* d_ws, size_t ws_size,
                              hipStream_t stream) {
    const float* X  = (const float*)d_in[0];
    const float* Wq = (const float*)d_in[1];
    const float* bq = (const float*)d_in[2];
    const float* Wk = (const float*)d_in[3];
    const float* bk = (const float*)d_in[4];
    const float* Wv = (const float*)d_in[5];
    const float* bv = (const float*)d_in[6];

    float* ctx   = (float*)d_out;
    float* probs = ctx + (size_t)B_ * S_ * D_;

    unsigned short* Xb = (unsigned short*)probs;            // staged in probs region
    unsigned short* Wb = Xb + (size_t)MP * 768;

    unsigned short* Qf = (unsigned short*)d_ws;
    unsigned short* Kf = Qf + (size_t)7864320;
    unsigned short* Vf = Kf + (size_t)7864320;

    prep<<<dim3(1024), 256, 0, stream>>>(X, Wq, Wk, Wv, Xb, Wb, Vf);
    qkv_gemm<<<dim3(1314), 512, 0, stream>>>(Xb, Wb, bq, bk, bv, Qf, Kf, Vf);
    attn<<<dim3(7104), 256, 0, stream>>>(Qf, Kf, Vf, ctx, probs);
}